// Round 7
// baseline (7036.163 us; speedup 1.0000x reference)
//
#include <hip/hip_runtime.h>
#include <hip/hip_bf16.h>

typedef __hip_bfloat16 bf16;
typedef _Float16 h16;
typedef __attribute__((ext_vector_type(8))) _Float16 half8;
typedef __attribute__((ext_vector_type(4))) _Float16 half4;
typedef __attribute__((ext_vector_type(4))) float f32x4;

#define NQ 128
#define HD 512
#define FD 256
#define NC 6
#define IMH 48
#define IMW 120
#define HW 5760   // 48*120

#define MEGA_GRID 512   // LDS 59904B -> exactly 2 blocks/CU -> 512 co-resident

__device__ __forceinline__ half8 pack8(float4 x, float4 y) {
    half8 h;
    h[0] = (h16)x.x; h[1] = (h16)x.y; h[2] = (h16)x.z; h[3] = (h16)x.w;
    h[4] = (h16)y.x; h[5] = (h16)y.y; h[6] = (h16)y.z; h[7] = (h16)y.w;
    return h;
}

// ---------------------------------------------------------------------------
// Manual grid barrier: monotonic counter, device(agent)-scope atomics+fences.
// Counter zeroed by prep2_k (stream-ordered before mega_k). All blocks call
// the same number of times; tgt advances by nb per call.
// ---------------------------------------------------------------------------
__device__ __forceinline__ void gbar(unsigned* bar, unsigned nb, unsigned* tgt)
{
    __syncthreads();
    if (threadIdx.x == 0) {
        *tgt += nb;
        __threadfence();
        __hip_atomic_fetch_add(bar, 1u, __ATOMIC_RELEASE, __HIP_MEMORY_SCOPE_AGENT);
        unsigned v;
        do {
            __builtin_amdgcn_s_sleep(2);
            v = __hip_atomic_load(bar, __ATOMIC_ACQUIRE, __HIP_MEMORY_SCOPE_AGENT);
        } while (v < *tgt);
        __threadfence();
    }
    __syncthreads();
}

// ---------------------------------------------------------------------------
// Weight swizzle descriptor: 11 fp32 row-major matrices -> fp16 MFMA B tiles.
// Global tile g holds: lane l -> W[n64*64 + ct*16 + (l&15)][ks*32 + (l>>4)*8 + j]
// where local = g - tileStart[w] = (n64*(K/32) + ks)*4 + ct.
// ---------------------------------------------------------------------------
struct SwzDesc {
    const float* src[11];
    unsigned int tileStart[12];    // 12th = sentinel (total tiles)
    int K[11];
};

// ---------------------------------------------------------------------------
// prep2: grid-stride fused prep, 2160 blocks x 256 (verified round 5) +
// zeroing of the mega barrier counter.
// ---------------------------------------------------------------------------
__global__ __launch_bounds__(256) void prep2_k(SwzDesc d, h16* __restrict__ swz,
                                               const float* __restrict__ feat,
                                               bf16* __restrict__ feat_t,
                                               const float* __restrict__ q0,
                                               h16* __restrict__ q016,
                                               unsigned* __restrict__ bar)
{
    __shared__ float tile[64 * 65];   // transpose staging only
    int bid = blockIdx.x, t = threadIdx.x;

    if (bid == 0 && t == 0) *bar = 0u;

    if (bid < 1536) {
        int wid = bid * 4 + (t >> 6);
        int l = t & 63;
        int lr = l & 15, q8 = (l >> 4) * 8;
        int total = (int)d.tileStart[11];
#pragma unroll 2
        for (int g = wid; g < total; g += 6144) {
            int w = 0;
            while (w < 10 && g >= (int)d.tileStart[w + 1]) w++;
            int local = g - (int)d.tileStart[w];
            int K = d.K[w];
            int K32 = K >> 5;
            int n64 = local / (K32 * 4);
            int rem = local - n64 * (K32 * 4);
            int ks = rem >> 2, ct = rem & 3;
            int row = n64 * 64 + ct * 16 + lr;
            int col = ks * 32 + q8;
            const float* sp = d.src[w] + (size_t)row * K + col;
            float4 u = *(const float4*)sp;
            float4 v = *(const float4*)(sp + 4);
            *(half8*)(swz + (size_t)g * 512 + l * 8) = pack8(u, v);
        }
    } else if (bid < 2152) {
        for (int g = bid - 1536; g < 2160; g += 616) {
            int cam = g / 360;
            int r = g - cam * 360;
            int fd_t = r / 90, hw_t = r - fd_t * 90;
            int hw0 = hw_t * 64, fd0 = fd_t * 64;
            const float* fb = feat + (size_t)cam * FD * HW;
            int fr_b = t >> 4, c4 = (t & 15) * 4;
#pragma unroll
            for (int p = 0; p < 4; p++) {
                int fr = p * 16 + fr_b;
                float4 u = *(const float4*)&fb[(size_t)(fd0 + fr) * HW + hw0 + c4];
                tile[fr * 65 + c4 + 0] = u.x;
                tile[fr * 65 + c4 + 1] = u.y;
                tile[fr * 65 + c4 + 2] = u.z;
                tile[fr * 65 + c4 + 3] = u.w;
            }
            __syncthreads();
            bf16* fo = feat_t + (size_t)cam * HW * FD;
            int hr_b = t >> 3, j = t & 7;
#pragma unroll
            for (int s = 0; s < 2; s++) {
                int hr = s * 32 + hr_b;
                union { ushort us[8]; uint4 u4; } pk;
#pragma unroll
                for (int e = 0; e < 8; e++) {
                    bf16 b = __float2bfloat16(tile[(j * 8 + e) * 65 + hr]);
                    pk.us[e] = *(const ushort*)&b;
                }
                *(uint4*)&fo[(size_t)(hw0 + hr) * FD + fd0 + j * 8] = pk.u4;
            }
            __syncthreads();
        }
    } else {
        for (int i = (bid - 2152) * 256 + t; i < 16384; i += 2048) {
            float4 u = *(const float4*)(q0 + (size_t)i * 4);
            half4 h; h[0] = (h16)u.x; h[1] = (h16)u.y; h[2] = (h16)u.z; h[3] = (h16)u.w;
            *(half4*)(q016 + (size_t)i * 4) = h;
        }
    }
}

// ---------------------------------------------------------------------------
// Split-K-in-block MFMA GEMM body on swizzled fp16 weights (unchanged).
// ---------------------------------------------------------------------------
template<int CTN, int NSUM, bool A2SW, bool LNA>
__device__ __forceinline__ void gemm_body(int bx, int by, int tid,
    float* redu, float* sst, float* sst2,
    const h16* __restrict__ A16, int lda, int sumStride,
    const float* __restrict__ A32,
    const float* __restrict__ lng, const float* __restrict__ lnb,
    float* __restrict__ lnout,
    const h16* __restrict__ A2_16, int a2Start,
    const h16* __restrict__ Wswz,
    const float* __restrict__ B0, const float* __restrict__ B1, const float* __restrict__ B2s,
    const float* __restrict__ R, int ldr,
    float* __restrict__ C32, h16* __restrict__ C16, int ldc,
    int K, int act)
{
    int w = tid >> 6, l = tid & 63;
    int lr = l & 15, q4 = l >> 4;
    int m0 = by * 16;
    int n0 = bx * 16 * CTN;
    int row = m0 + lr;
    int K32 = K >> 5;
    int KQ = K32 >> 2;
    int ks0 = w * KQ;

    bool useA2 = A2SW && (bx >= a2Start);

    const float* arow32 = nullptr;
    float mean = 0.f, rstd = 1.f;
    if (LNA && !useA2) {
        arow32 = A32 + (size_t)row * K + q4 * 8;
        float s = 0.f, s2 = 0.f;
        for (int ks = ks0; ks < ks0 + KQ; ks++) {
            float4 u = *(const float4*)(arow32 + ks * 32);
            float4 v = *(const float4*)(arow32 + ks * 32 + 4);
            s  += u.x + u.y + u.z + u.w + v.x + v.y + v.z + v.w;
            s2 += u.x*u.x + u.y*u.y + u.z*u.z + u.w*u.w
                + v.x*v.x + v.y*v.y + v.z*v.z + v.w*v.w;
        }
        s  += __shfl_xor(s, 16);  s  += __shfl_xor(s, 32);
        s2 += __shfl_xor(s2, 16); s2 += __shfl_xor(s2, 32);
        if (q4 == 0) { sst[w * 16 + lr] = s; sst2[w * 16 + lr] = s2; }
        __syncthreads();
        float st = sst[lr] + sst[16 + lr] + sst[32 + lr] + sst[48 + lr];
        float st2 = sst2[lr] + sst2[16 + lr] + sst2[32 + lr] + sst2[48 + lr];
        mean = st * (1.0f / (float)K);
        float var = st2 * (1.0f / (float)K) - mean * mean;
        rstd = rsqrtf(var + 1e-5f);
    }

    const h16* arow16 = nullptr;
    if (useA2)       arow16 = A2_16 + (size_t)row * 512 + q4 * 8;
    else if (!LNA)   arow16 = A16 + (size_t)row * lda + q4 * 8;

    const h16* wbase[CTN];
#pragma unroll
    for (int ct = 0; ct < CTN; ct++) {
        int tct = (n0 >> 4) + ct;
        wbase[ct] = Wswz + (((size_t)(tct >> 2) * K32 * 4 + (tct & 3)) * 64 + l) * 8;
    }

    f32x4 acc[CTN];
#pragma unroll
    for (int ct = 0; ct < CTN; ct++) acc[ct] = (f32x4){0.f, 0.f, 0.f, 0.f};

    bool wrln = LNA && !useA2 && (bx == 0) && lnout;

#pragma unroll 4
    for (int ks = ks0; ks < ks0 + KQ; ks++) {
        half8 a;
        if (LNA && !useA2) {
            float4 u = *(const float4*)(arow32 + ks * 32);
            float4 v = *(const float4*)(arow32 + ks * 32 + 4);
            float4 g0 = *(const float4*)(lng + ks * 32 + q4 * 8);
            float4 g1 = *(const float4*)(lng + ks * 32 + q4 * 8 + 4);
            float4 b0 = *(const float4*)(lnb + ks * 32 + q4 * 8);
            float4 b1 = *(const float4*)(lnb + ks * 32 + q4 * 8 + 4);
            float4 o0, o1;
            o0.x = (u.x - mean) * rstd * g0.x + b0.x;
            o0.y = (u.y - mean) * rstd * g0.y + b0.y;
            o0.z = (u.z - mean) * rstd * g0.z + b0.z;
            o0.w = (u.w - mean) * rstd * g0.w + b0.w;
            o1.x = (v.x - mean) * rstd * g1.x + b1.x;
            o1.y = (v.y - mean) * rstd * g1.y + b1.y;
            o1.z = (v.z - mean) * rstd * g1.z + b1.z;
            o1.w = (v.w - mean) * rstd * g1.w + b1.w;
            if (wrln) {
                *(float4*)(lnout + (size_t)row * K + ks * 32 + q4 * 8)     = o0;
                *(float4*)(lnout + (size_t)row * K + ks * 32 + q4 * 8 + 4) = o1;
            }
            a = pack8(o0, o1);
        } else if (NSUM == 1) {
            a = *(const half8*)(arow16 + (size_t)ks * 32);
        } else {
            float s[8] = {0.f, 0.f, 0.f, 0.f, 0.f, 0.f, 0.f, 0.f};
#pragma unroll
            for (int j = 0; j < NSUM; j++) {
                half8 tt = *(const half8*)(arow16 + (size_t)j * sumStride + ks * 32);
#pragma unroll
                for (int e = 0; e < 8; e++) s[e] += (float)tt[e];
            }
#pragma unroll
            for (int e = 0; e < 8; e++) a[e] = (h16)s[e];
        }
#pragma unroll
        for (int ct = 0; ct < CTN; ct++) {
            half8 bfr = *(const half8*)(wbase[ct] + (size_t)ks * 2048);
            acc[ct] = __builtin_amdgcn_mfma_f32_16x16x32_f16(a, bfr, acc[ct], 0, 0, 0);
        }
    }

#pragma unroll
    for (int ct = 0; ct < CTN; ct++)
        *(f32x4*)&redu[(size_t)(w * CTN + ct) * 256 + l * 4] = acc[ct];
    __syncthreads();

    if (w < CTN) {
        int ct = w;
        f32x4 sum = *(const f32x4*)&redu[(size_t)ct * 256 + l * 4];
#pragma unroll
        for (int w2 = 1; w2 < 4; w2++) {
            f32x4 tt = *(const f32x4*)&redu[(size_t)(w2 * CTN + ct) * 256 + l * 4];
            sum[0] += tt[0]; sum[1] += tt[1]; sum[2] += tt[2]; sum[3] += tt[3];
        }
        int n = n0 + ct * 16 + lr;
        float bv;
        if (B1) { int sec = n >> 9, ni = n & 511;
                  bv = (sec == 0) ? B0[ni] : (sec == 1 ? B1[ni] : B2s[ni]); }
        else bv = B0[n];
#pragma unroll
        for (int r = 0; r < 4; r++) {
            int m = m0 + q4 * 4 + r;
            float v = sum[r] + bv;
            if (act) v = fmaxf(v, 0.f);
            if (R) v += R[(size_t)m * ldr + n];
            if (C32) C32[(size_t)m * ldc + n] = v;
            if (C16) C16[(size_t)m * ldc + n] = (h16)v;
        }
    }
}

// ---- head output body: one wave per (q, n) ----
__device__ __forceinline__ void heads2_body(int q, int n, int lane,
    const h16* __restrict__ hid16,
    const float* __restrict__ w2m, const float* __restrict__ b2m,
    const float* __restrict__ w2t, const float* __restrict__ b2t,
    const float* __restrict__ w2a, const float* __restrict__ b2a,
    const float* __restrict__ pmin, const float* __restrict__ pmax,
    float* __restrict__ out)
{
    const float* wr; float bv; int mode, sect;
    if (n < 11)      { sect = 0; wr = w2m + n * 512;        bv = b2m[n];      mode = 0; }
    else if (n < 21) { sect = 1; wr = w2t + (n - 11) * 512; bv = b2t[n - 11]; mode = 1; }
    else             { sect = 2; wr = w2a + (n - 21) * 512; bv = b2a[n - 21]; mode = 2; }
    half8 hv = *(const half8*)(hid16 + q * 1536 + sect * 512 + lane * 8);
    const float4* w4 = (const float4*)(wr + lane * 8);
    float4 c0 = w4[0], c1 = w4[1];
    float acc = (float)hv[0] * c0.x + (float)hv[1] * c0.y
              + (float)hv[2] * c0.z + (float)hv[3] * c0.w
              + (float)hv[4] * c1.x + (float)hv[5] * c1.y
              + (float)hv[6] * c1.z + (float)hv[7] * c1.w;
    for (int off = 32; off; off >>= 1) acc += __shfl_xor(acc, off);
    if (lane == 0) {
        float v = acc + bv;
        if (mode == 0)      v = (1.0f / (1.0f + __expf(-v))) * (pmax[n] - pmin[n]) + pmin[n];
        else if (mode == 2) v = 1.0f / (1.0f + __expf(-v));
        out[q * 24 + n] = v;
    }
}

// ---- MHA core body on packed qkv (128 x 1536 = [Q|K|V] fp32) ----
__device__ __forceinline__ void attn_body(int bid, int tid,
                                          float* KVl, float* Ql, float* Pl,
                                          const float* __restrict__ qkv,
                                          h16* __restrict__ out16)
{
    int h = bid >> 2, chunk = bid & 3;

    for (int l = tid; l < 2048; l += 256) {
        int row = l >> 4, c4 = (l & 15) * 4;
        float4 v = *(const float4*)&qkv[row * 1536 + 512 + h * 64 + c4];
        *(float4*)&KVl[row * 68 + c4] = v;
    }
    for (int l = tid; l < 512; l += 256) {
        int row = l >> 4, c4 = (l & 15) * 4;
        float4 v = *(const float4*)&qkv[(chunk * 32 + row) * 1536 + h * 64 + c4];
        *(float4*)&Ql[row * 68 + c4] = v;
    }
    __syncthreads();

    int w = tid >> 6, j = tid & 63;
    for (int r8 = 0; r8 < 8; r8++) {
        int lr = w * 8 + r8;
        float s0 = 0.f, s1 = 0.f;
#pragma unroll
        for (int k4 = 0; k4 < 64; k4 += 4) {
            float4 qv  = *(const float4*)&Ql[lr * 68 + k4];
            float4 k0v = *(const float4*)&KVl[j * 68 + k4];
            float4 k1v = *(const float4*)&KVl[(j + 64) * 68 + k4];
            s0 += qv.x * k0v.x + qv.y * k0v.y + qv.z * k0v.z + qv.w * k0v.w;
            s1 += qv.x * k1v.x + qv.y * k1v.y + qv.z * k1v.z + qv.w * k1v.w;
        }
        s0 *= 0.125f; s1 *= 0.125f;
        float m = fmaxf(s0, s1);
        for (int off = 32; off; off >>= 1) m = fmaxf(m, __shfl_xor(m, off));
        float e0 = __expf(s0 - m), e1 = __expf(s1 - m);
        float sm = e0 + e1;
        for (int off = 32; off; off >>= 1) sm += __shfl_xor(sm, off);
        float inv = 1.0f / sm;
        Pl[lr * 128 + j]      = e0 * inv;
        Pl[lr * 128 + j + 64] = e1 * inv;
    }
    __syncthreads();

    for (int l = tid; l < 2048; l += 256) {
        int row = l >> 4, c4 = (l & 15) * 4;
        float4 v = *(const float4*)&qkv[row * 1536 + 1024 + h * 64 + c4];
        KVl[(c4 + 0) * 132 + row] = v.x;
        KVl[(c4 + 1) * 132 + row] = v.y;
        KVl[(c4 + 2) * 132 + row] = v.z;
        KVl[(c4 + 3) * 132 + row] = v.w;
    }
    __syncthreads();

    int d = tid & 63, w2 = tid >> 6;
    for (int r8 = 0; r8 < 8; r8++) {
        int lr = w2 * 8 + r8;
        float o = 0.f;
#pragma unroll
        for (int j4 = 0; j4 < 128; j4 += 4) {
            float4 pv = *(const float4*)&Pl[lr * 128 + j4];
            float4 vv = *(const float4*)&KVl[d * 132 + j4];
            o += pv.x * vv.x + pv.y * vv.y + pv.z * vv.z + pv.w * vv.w;
        }
        out16[(chunk * 32 + lr) * 512 + h * 64 + d] = (h16)o;
    }
}

// ---- gather body (no early return; mega-safe) ----
__device__ __forceinline__ float bflo(unsigned u) {
    union { unsigned i; float f; } c; c.i = u << 16; return c.f;
}
__device__ __forceinline__ float bfhi(unsigned u) {
    union { unsigned i; float f; } c; c.i = u & 0xffff0000u; return c.f;
}

__device__ __forceinline__ void gather_body(int n, int cam, int tid, float* smem,
                                            const bf16* __restrict__ ft,
                                            const float* __restrict__ proj,
                                            const float* __restrict__ preds,
                                            h16* __restrict__ agg16)
{
    float* part = smem;                    // 2048 floats
    float* mo   = smem + 2048;             // 11
    float* gw   = smem + 2064;             // 384
    int*   goff = (int*)(smem + 2448);     // 384
    int*   cnt  = (int*)(smem + 2832);

    if (tid == 0) *cnt = 0;
    if (tid < 11) mo[tid] = preds[n * 24 + tid];
    __syncthreads();

    if (tid < 96) {
        int p = tid;
        float dd0 = mo[8], dd1 = mo[9], dd2 = mo[10];
        float c0 = mo[0], c1 = mo[1], c2 = mo[2];
        float sy, cy;
        sincosf(mo[7], &sy, &cy);
        int face = p >> 4, axis = face >> 1;
        float sgn = (face & 1) ? 0.5f : -0.5f;
        float offi = -0.4f + (float)((p >> 2) & 3) * (0.8f / 3.0f);
        float offj = -0.4f + (float)(p & 3) * (0.8f / 3.0f);
        float t0, t1, t2;
        if (axis == 0)      { t0 = sgn;  t1 = offi; t2 = offj; }
        else if (axis == 1) { t0 = offi; t1 = sgn;  t2 = offj; }
        else                { t0 = offi; t1 = offj; t2 = sgn;  }
        float px = t0 * dd0, py = t1 * dd1, pz = t2 * dd2;
        float X = px * cy - py * sy + c0;
        float Y = px * sy + py * cy + c1;
        float Z = pz + c2;
        const float* P = proj + cam * 12;
        float cu = P[0] * X + P[1] * Y + P[2] * Z + P[3];
        float cv = P[4] * X + P[5] * Y + P[6] * Z + P[7];
        float cz = P[8] * X + P[9] * Y + P[10] * Z + P[11];
        float zs = (fabsf(cz) > 1e-6f) ? cz : 1e-6f;
        float u = cu / zs, v = cv / zs;
        bool front = cz > 0.0f;
        float u0 = floorf(u), v0 = floorf(v);
        float du = u - u0, dv = v - v0;
        float us[4] = {u0, u0 + 1.0f, u0, u0 + 1.0f};
        float vs[4] = {v0, v0, v0 + 1.0f, v0 + 1.0f};
        float wt[4] = {(1.0f - du) * (1.0f - dv), du * (1.0f - dv),
                       (1.0f - du) * dv, du * dv};
        int   myoff[4]; float myw[4]; int k = 0;
#pragma unroll
        for (int t = 0; t < 4; t++) {
            bool ok = front && (us[t] >= 0.0f) && (us[t] <= 119.0f)
                            && (vs[t] >= 0.0f) && (vs[t] <= 47.0f)
                            && (wt[t] > 0.0f);
            if (ok) {
                myoff[k] = ((int)vs[t] * IMW + (int)us[t]) * FD;
                myw[k]   = wt[t];
                k++;
            }
        }
        if (k) {
            int base = atomicAdd(cnt, k);
            for (int s = 0; s < k; s++) { goff[base + s] = myoff[s]; gw[base + s] = myw[s]; }
        }
    }
    __syncthreads();
    int C = *cnt;
    h16* slab = agg16 + (size_t)cam * 32768 + n * 256;
    if (C == 0) {
        slab[tid] = (h16)0.f;
    } else {
        int g8  = (tid & 31) * 8;
        int row = tid >> 5;
        const bf16* fb = ft + (size_t)cam * HW * FD + g8;
        float acc[8] = {0.f, 0.f, 0.f, 0.f, 0.f, 0.f, 0.f, 0.f};
        for (int e = row; e < C; e += 8) {
            float w = gw[e];
            uint4 rv = *(const uint4*)(fb + goff[e]);
            acc[0] += w * bflo(rv.x); acc[1] += w * bfhi(rv.x);
            acc[2] += w * bflo(rv.y); acc[3] += w * bfhi(rv.y);
            acc[4] += w * bflo(rv.z); acc[5] += w * bfhi(rv.z);
            acc[6] += w * bflo(rv.w); acc[7] += w * bfhi(rv.w);
        }
#pragma unroll
        for (int j = 0; j < 8; j++) part[row * 256 + g8 + j] = acc[j];
        __syncthreads();
        float s = 0.f;
#pragma unroll
        for (int r = 0; r < 8; r++) s += part[r * 256 + tid];
        slab[tid] = (h16)(s * (1.0f / 576.0f));
    }
}

// ---------------------------------------------------------------------------
// Mega kernel: entire 6-layer decoder loop, persistent, manual grid barrier.
// ---------------------------------------------------------------------------
struct MegaP {
    const h16* swz;
    const float* queries0;
    const h16* q016;
    const bf16* feat_t;
    const float* proj;
    const float *motion_b1, *type_b1, *attr_b1;
    const float *motion_w2, *motion_b2, *type_w2, *type_b2, *attr_w2, *attr_b2;
    const float *pmin, *pmax;
    const float *fmlp_b1, *fmlp_b2;
    const float *sa_in_b, *sa_out_b, *fa_in_b, *fa_out_b, *ffn_b1, *ffn_b2;
    const float *ln1_g, *ln1_b, *ln2_g, *ln2_b, *ln3_g, *ln3_b;
    h16 *hid16, *agg16, *fmlph16, *feath16, *attnb16, *ffnh16, *qn16;
    float *qkv, *lnx, *x1, *x2, *qn32;
    float* out;
    unsigned* bar;
};

__global__ __launch_bounds__(256, 2) void mega_k(MegaP P)
{
    __shared__ float smem[14976];   // 59904B: attn KVl 8704 | Ql 2176 | Pl 4096
    int bid = blockIdx.x, tid = threadIdx.x;
    int GS = gridDim.x;
    unsigned tgt = 0;

    const h16* sw_heads = P.swz;
    const h16* sw_fmlp1 = P.swz + 786432;
    const h16* sw_fmlp2 = P.swz + 917504;
    const h16* sw_sain  = P.swz + 1179648;
    const h16* sw_saout = P.swz + 5898240;
    const h16* sw_fain  = P.swz + 7471104;
    const h16* sw_faout = P.swz + 12189696;
    const h16* sw_ffn1  = P.swz + 13762560;
    const h16* sw_ffn2  = P.swz + 20054016;

    const h16*   q16 = P.q016;
    const float* q32 = P.queries0;

    for (int i = 0; i < 6; i++) {
        // P1: heads hidden GEMM (384 units)
        for (int u = bid; u < 384; u += GS) {
            __syncthreads();
            gemm_body<2, 1, false, false>(u % 48, u / 48, tid,
                smem, smem + 2048, smem + 2112,
                q16, 512, 0, nullptr, nullptr, nullptr, nullptr, nullptr, 0,
                sw_heads, P.motion_b1, P.type_b1, P.attr_b1, nullptr, 0,
                nullptr, P.hid16, 1536, 512, 1);
        }
        gbar(P.bar, GS, &tgt);

        if (i == 5) {
            // final heads2 only (768 units x 4 waves)
            for (int u = bid; u < 768; u += GS) {
                int p = (u << 2) + (tid >> 6);
                heads2_body(p / 24, p % 24, tid & 63, P.hid16,
                            P.motion_w2, P.motion_b2, P.type_w2, P.type_b2,
                            P.attr_w2, P.attr_b2, P.pmin, P.pmax, P.out + i * 3072);
            }
            break;
        }

        // P2: sa_in GEMM (384) + heads2 (768)
        for (int u = bid; u < 1152; u += GS) {
            __syncthreads();
            if (u < 384) {
                gemm_body<2, 1, false, true>(u % 48, u / 48, tid,
                    smem, smem + 2048, smem + 2112,
                    nullptr, 0, 0, q32, P.ln1_g + i * 512, P.ln1_b + i * 512, P.lnx,
                    nullptr, 0,
                    sw_sain + (size_t)i * 786432, P.sa_in_b + i * 1536, nullptr, nullptr,
                    nullptr, 0, P.qkv, nullptr, 1536, 512, 0);
            } else {
                int p = ((u - 384) << 2) + (tid >> 6);
                heads2_body(p / 24, p % 24, tid & 63, P.hid16,
                            P.motion_w2, P.motion_b2, P.type_w2, P.type_b2,
                            P.attr_w2, P.attr_b2, P.pmin, P.pmax, P.out + i * 3072);
            }
        }
        gbar(P.bar, GS, &tgt);

        // P3: attn-self (32) + gather (768)
        for (int u = bid; u < 800; u += GS) {
            __syncthreads();
            if (u < 32) {
                attn_body(u, tid, smem, smem + 8704, smem + 10880, P.qkv, P.attnb16);
            } else {
                int v = u - 32;
                gather_body(v % 128, v / 128, tid, smem, P.feat_t, P.proj,
                            P.out + i * 3072, P.agg16);
            }
        }
        gbar(P.bar, GS, &tgt);

        // P4: fmlp1 (256) + sa_out (256)
        for (int u = bid; u < 512; u += GS) {
            __syncthreads();
            if (u < 256) {
                gemm_body<1, 6, false, false>(u % 32, u / 32, tid,
                    smem, smem + 1024, smem + 1088,
                    P.agg16, 256, 32768, nullptr, nullptr, nullptr, nullptr, nullptr, 0,
                    sw_fmlp1, P.fmlp_b1, nullptr, nullptr, nullptr, 0,
                    nullptr, P.fmlph16, 512, 256, 1);
            } else {
                int v = u - 256;
                gemm_body<1, 1, false, false>(v % 32, v / 32, tid,
                    smem, smem + 1024, smem + 1088,
                    P.attnb16, 512, 0, nullptr, nullptr, nullptr, nullptr, nullptr, 0,
                    sw_saout + (size_t)i * 262144, P.sa_out_b + i * 512, nullptr, nullptr,
                    P.lnx, 512, P.x1, nullptr, 512, 512, 0);
            }
        }
        gbar(P.bar, GS, &tgt);

        // P5: fmlp2 (256)
        for (int u = bid; u < 256; u += GS) {
            __syncthreads();
            gemm_body<1, 1, false, false>(u % 32, u / 32, tid,
                smem, smem + 1024, smem + 1088,
                P.fmlph16, 512, 0, nullptr, nullptr, nullptr, nullptr, nullptr, 0,
                sw_fmlp2, P.fmlp_b2, nullptr, nullptr, nullptr, 0,
                nullptr, P.feath16, 512, 512, 0);
        }
        gbar(P.bar, GS, &tgt);

        // P6: fa_in (384; kv side reads feath16 for bx>=16)
        for (int u = bid; u < 384; u += GS) {
            __syncthreads();
            gemm_body<2, 1, true, true>(u % 48, u / 48, tid,
                smem, smem + 2048, smem + 2112,
                nullptr, 0, 0, P.x1, P.ln2_g + i * 512, P.ln2_b + i * 512, P.lnx,
                P.feath16, 16,
                sw_fain + (size_t)i * 786432, P.fa_in_b + i * 1536, nullptr, nullptr,
                nullptr, 0, P.qkv, nullptr, 1536, 512, 0);
        }
        gbar(P.bar, GS, &tgt);

        // P7: attn-cross (32)
        for (int u = bid; u < 32; u += GS) {
            __syncthreads();
            attn_body(u, tid, smem, smem + 8704, smem + 10880, P.qkv, P.attnb16);
        }
        gbar(P.bar, GS, &tgt);

        // P8: fa_out (256)
        for (int u = bid; u < 256; u += GS) {
            __syncthreads();
            gemm_body<1, 1, false, false>(u % 32, u / 32, tid,
                smem, smem + 1024, smem + 1088,
                P.attnb16, 512, 0, nullptr, nullptr, nullptr, nullptr, nullptr, 0,
                sw_faout + (size_t)i * 262144, P.fa_out_b + i * 512, nullptr, nullptr,
                P.lnx, 512, P.x2, nullptr, 512, 512, 0);
        }
        gbar(P.bar, GS, &tgt);

        // P9: ffn1 (512)
        for (int u = bid; u < 512; u += GS) {
            __syncthreads();
            gemm_body<2, 1, false, true>(u % 64, u / 64, tid,
                smem, smem + 2048, smem + 2112,
                nullptr, 0, 0, P.x2, P.ln3_g + i * 512, P.ln3_b + i * 512, P.lnx,
                nullptr, 0,
                sw_ffn1 + (size_t)i * 1048576, P.ffn_b1 + i * 2048, nullptr, nullptr,
                nullptr, 0, nullptr, P.ffnh16, 2048, 512, 1);
        }
        gbar(P.bar, GS, &tgt);

        // P10: ffn2 (256)
        for (int u = bid; u < 256; u += GS) {
            __syncthreads();
            gemm_body<1, 1, false, false>(u % 32, u / 32, tid,
                smem, smem + 1024, smem + 1088,
                P.ffnh16, 2048, 0, nullptr, nullptr, nullptr, nullptr, nullptr, 0,
                sw_ffn2 + (size_t)i * 1048576, P.ffn_b2 + i * 512, nullptr, nullptr,
                P.lnx, 512, P.qn32, P.qn16, 512, 2048, 0);
        }
        gbar(P.bar, GS, &tgt);

        q16 = P.qn16;
        q32 = P.qn32;
    }
}

// ---------------------------------------------------------------------------
extern "C" void kernel_launch(void* const* d_in, const int* in_sizes, int n_in,
                              void* d_out, int out_size, void* d_ws, size_t ws_size,
                              hipStream_t stream)
{
    const float* features  = (const float*)d_in[0];
    const float* proj      = (const float*)d_in[1];
    const float* queries0  = (const float*)d_in[3];
    const float* pmin      = (const float*)d_in[4];
    const float* pmax      = (const float*)d_in[5];
    const float* motion_w1 = (const float*)d_in[6];
    const float* motion_b1 = (const float*)d_in[7];
    const float* motion_w2 = (const float*)d_in[8];
    const float* motion_b2 = (const float*)d_in[9];
    const float* type_w1   = (const float*)d_in[10];
    const float* type_b1   = (const float*)d_in[11];
    const float* type_w2   = (const float*)d_in[12];
    const float* type_b2   = (const float*)d_in[13];
    const float* attr_w1   = (const float*)d_in[14];
    const float* attr_b1   = (const float*)d_in[15];
    const float* attr_w2   = (const float*)d_in[16];
    const float* attr_b2   = (const float*)d_in[17];
    const float* fmlp_w1   = (const float*)d_in[18];
    const float* fmlp_b1   = (const float*)d_in[19];
    const float* fmlp_w2   = (const float*)d_in[20];
    const float* fmlp_b2   = (const float*)d_in[21];
    const float* sa_in_w   = (const float*)d_in[22];
    const float* sa_in_b   = (const float*)d_in[23];
    const float* sa_out_w  = (const float*)d_in[24];
    const float* sa_out_b  = (const float*)d_in[25];
    const float* fa_in_w   = (const float*)d_in[26];
    const float* fa_in_b   = (const float*)d_in[27];
    const float* fa_out_w  = (const float*)d_in[28];
    const float* fa_out_b  = (const float*)d_in[29];
    const float* ffn_w1    = (const float*)d_in[30];
    const float* ffn_b1    = (const float*)d_in[31];
    const float* ffn_w2    = (const float*)d_in[32];
    const float* ffn_b2    = (const float*)d_in[33];
    const float* ln1_g     = (const float*)d_in[34];
    const float* ln1_b     = (const float*)d_in[35];
    const float* ln2_g     = (const float*)d_in[36];
    const float* ln2_b     = (const float*)d_in[37];
    const float* ln3_g     = (const float*)d_in[38];
    const float* ln3_b     = (const float*)d_in[39];
    float* out = (float*)d_out;

    // ---- workspace ----
    char* p = (char*)d_ws;
    bf16* feat_t = (bf16*)p;   p += (size_t)NC * HW * FD * 2;        // 17.7 MB
    h16* swz     = (h16*)p;    p += (size_t)51456 * 512 * 2;         // 52.7 MB
    h16* q016    = (h16*)p;    p += 65536 * 2;
    h16* hid16   = (h16*)p;    p += 196608 * 2;
    h16* agg16   = (h16*)p;    p += 196608 * 2;
    h16* fmlph16 = (h16*)p;    p += 65536 * 2;
    h16* feath16 = (h16*)p;    p += 65536 * 2;
    h16* attnb16 = (h16*)p;    p += 65536 * 2;
    h16* ffnh16  = (h16*)p;    p += 262144 * 2;
    h16* qn16    = (h16*)p;    p += 65536 * 2;
    float* qkv   = (float*)p;  p += 196608 * 4;
    float* lnx   = (float*)p;  p += 65536 * 4;
    float* x1    = (float*)p;  p += 65536 * 4;
    float* x2    = (float*)p;  p += 65536 * 4;
    float* qn32  = (float*)p;  p += 65536 * 4;
    unsigned* bar = (unsigned*)p; p += 256;

    // ---- one-time prep (direct swizzle + transpose + cvt + bar zero) ----
    SwzDesc sd;
    const float* srcs[11] = {motion_w1, type_w1, attr_w1, fmlp_w1, fmlp_w2,
                             sa_in_w, sa_out_w, fa_in_w, fa_out_w, ffn_w1, ffn_w2};
    int Ks[11]    = {512, 512, 512, 256, 512, 512, 512, 512, 512, 512, 2048};
    int tiles[11] = {512, 512, 512, 256, 512, 9216, 3072, 9216, 3072, 12288, 12288};
    unsigned int cumT = 0;
    for (int i = 0; i < 11; i++) {
        sd.src[i] = srcs[i]; sd.K[i] = Ks[i];
        sd.tileStart[i] = cumT;
        cumT += tiles[i];
    }
    sd.tileStart[11] = cumT;   // 51456

    prep2_k<<<2160, 256, 0, stream>>>(sd, swz, features, feat_t, queries0, q016, bar);

    // ---- mega kernel (persistent, manual barrier) ----
    MegaP mp;
    mp.swz = swz; mp.queries0 = queries0; mp.q016 = q016;
    mp.feat_t = feat_t; mp.proj = proj;
    mp.motion_b1 = motion_b1; mp.type_b1 = type_b1; mp.attr_b1 = attr_b1;
    mp.motion_w2 = motion_w2; mp.motion_b2 = motion_b2;
    mp.type_w2 = type_w2; mp.type_b2 = type_b2;
    mp.attr_w2 = attr_w2; mp.attr_b2 = attr_b2;
    mp.pmin = pmin; mp.pmax = pmax;
    mp.fmlp_b1 = fmlp_b1; mp.fmlp_b2 = fmlp_b2;
    mp.sa_in_b = sa_in_b; mp.sa_out_b = sa_out_b;
    mp.fa_in_b = fa_in_b; mp.fa_out_b = fa_out_b;
    mp.ffn_b1 = ffn_b1; mp.ffn_b2 = ffn_b2;
    mp.ln1_g = ln1_g; mp.ln1_b = ln1_b; mp.ln2_g = ln2_g; mp.ln2_b = ln2_b;
    mp.ln3_g = ln3_g; mp.ln3_b = ln3_b;
    mp.hid16 = hid16; mp.agg16 = agg16; mp.fmlph16 = fmlph16;
    mp.feath16 = feath16; mp.attnb16 = attnb16; mp.ffnh16 = ffnh16;
    mp.qn16 = qn16;
    mp.qkv = qkv; mp.lnx = lnx; mp.x1 = x1; mp.x2 = x2; mp.qn32 = qn32;
    mp.out = out;
    mp.bar = bar;

    mega_k<<<MEGA_GRID, 256, 0, stream>>>(mp);
}

// Round 8
// 2788.866 us; speedup vs baseline: 2.5229x; 2.5229x over previous
//
#include <hip/hip_runtime.h>
#include <hip/hip_bf16.h>

typedef __hip_bfloat16 bf16;
typedef _Float16 h16;
typedef __attribute__((ext_vector_type(8))) _Float16 half8;
typedef __attribute__((ext_vector_type(4))) _Float16 half4;
typedef __attribute__((ext_vector_type(4))) float f32x4;

#define NQ 128
#define HD 512
#define FD 256
#define NC 6
#define IMH 48
#define IMW 120
#define HW 5760   // 48*120

#define MEGA_GRID 512   // LDS 59904B -> exactly 2 blocks/CU -> 512 co-resident

__device__ __forceinline__ half8 pack8(float4 x, float4 y) {
    half8 h;
    h[0] = (h16)x.x; h[1] = (h16)x.y; h[2] = (h16)x.z; h[3] = (h16)x.w;
    h[4] = (h16)y.x; h[5] = (h16)y.y; h[6] = (h16)y.z; h[7] = (h16)y.w;
    return h;
}

// ---------------------------------------------------------------------------
// Manual grid barrier, monotonic counter. Round-7 version invalidated L2 on
// EVERY poll (acquire per load -> 309MB refetch, 6850us). Fixed protocol:
//   signal : fetch_add RELEASE (one L2 writeback, publishes this XCD's writes)
//   spin   : RELAXED atomic loads (coherent read path, NO cache invalidate)
//   exit   : ONE acquire fence (single L1+L2 invalidate, then refill from L3)
// ---------------------------------------------------------------------------
__device__ __forceinline__ void gbar(unsigned* bar, unsigned nb, unsigned* tgt)
{
    __syncthreads();
    if (threadIdx.x == 0) {
        *tgt += nb;
        __hip_atomic_fetch_add(bar, 1u, __ATOMIC_RELEASE, __HIP_MEMORY_SCOPE_AGENT);
        unsigned v;
        do {
            __builtin_amdgcn_s_sleep(8);
            v = __hip_atomic_load(bar, __ATOMIC_RELAXED, __HIP_MEMORY_SCOPE_AGENT);
        } while (v < *tgt);
        __builtin_amdgcn_fence(__ATOMIC_ACQUIRE, "agent");
    }
    __syncthreads();
}

// ---------------------------------------------------------------------------
// Weight swizzle descriptor: 11 fp32 row-major matrices -> fp16 MFMA B tiles.
// Global tile g holds: lane l -> W[n64*64 + ct*16 + (l&15)][ks*32 + (l>>4)*8 + j]
// where local = g - tileStart[w] = (n64*(K/32) + ks)*4 + ct.
// ---------------------------------------------------------------------------
struct SwzDesc {
    const float* src[11];
    unsigned int tileStart[12];    // 12th = sentinel (total tiles)
    int K[11];
};

// ---------------------------------------------------------------------------
// prep2: grid-stride fused prep, 2160 blocks x 256 (verified round 5) +
// zeroing of the mega barrier counter.
// ---------------------------------------------------------------------------
__global__ __launch_bounds__(256) void prep2_k(SwzDesc d, h16* __restrict__ swz,
                                               const float* __restrict__ feat,
                                               bf16* __restrict__ feat_t,
                                               const float* __restrict__ q0,
                                               h16* __restrict__ q016,
                                               unsigned* __restrict__ bar)
{
    __shared__ float tile[64 * 65];   // transpose staging only
    int bid = blockIdx.x, t = threadIdx.x;

    if (bid == 0 && t == 0) *bar = 0u;

    if (bid < 1536) {
        int wid = bid * 4 + (t >> 6);
        int l = t & 63;
        int lr = l & 15, q8 = (l >> 4) * 8;
        int total = (int)d.tileStart[11];
#pragma unroll 2
        for (int g = wid; g < total; g += 6144) {
            int w = 0;
            while (w < 10 && g >= (int)d.tileStart[w + 1]) w++;
            int local = g - (int)d.tileStart[w];
            int K = d.K[w];
            int K32 = K >> 5;
            int n64 = local / (K32 * 4);
            int rem = local - n64 * (K32 * 4);
            int ks = rem >> 2, ct = rem & 3;
            int row = n64 * 64 + ct * 16 + lr;
            int col = ks * 32 + q8;
            const float* sp = d.src[w] + (size_t)row * K + col;
            float4 u = *(const float4*)sp;
            float4 v = *(const float4*)(sp + 4);
            *(half8*)(swz + (size_t)g * 512 + l * 8) = pack8(u, v);
        }
    } else if (bid < 2152) {
        for (int g = bid - 1536; g < 2160; g += 616) {
            int cam = g / 360;
            int r = g - cam * 360;
            int fd_t = r / 90, hw_t = r - fd_t * 90;
            int hw0 = hw_t * 64, fd0 = fd_t * 64;
            const float* fb = feat + (size_t)cam * FD * HW;
            int fr_b = t >> 4, c4 = (t & 15) * 4;
#pragma unroll
            for (int p = 0; p < 4; p++) {
                int fr = p * 16 + fr_b;
                float4 u = *(const float4*)&fb[(size_t)(fd0 + fr) * HW + hw0 + c4];
                tile[fr * 65 + c4 + 0] = u.x;
                tile[fr * 65 + c4 + 1] = u.y;
                tile[fr * 65 + c4 + 2] = u.z;
                tile[fr * 65 + c4 + 3] = u.w;
            }
            __syncthreads();
            bf16* fo = feat_t + (size_t)cam * HW * FD;
            int hr_b = t >> 3, j = t & 7;
#pragma unroll
            for (int s = 0; s < 2; s++) {
                int hr = s * 32 + hr_b;
                union { ushort us[8]; uint4 u4; } pk;
#pragma unroll
                for (int e = 0; e < 8; e++) {
                    bf16 b = __float2bfloat16(tile[(j * 8 + e) * 65 + hr]);
                    pk.us[e] = *(const ushort*)&b;
                }
                *(uint4*)&fo[(size_t)(hw0 + hr) * FD + fd0 + j * 8] = pk.u4;
            }
            __syncthreads();
        }
    } else {
        for (int i = (bid - 2152) * 256 + t; i < 16384; i += 2048) {
            float4 u = *(const float4*)(q0 + (size_t)i * 4);
            half4 h; h[0] = (h16)u.x; h[1] = (h16)u.y; h[2] = (h16)u.z; h[3] = (h16)u.w;
            *(half4*)(q016 + (size_t)i * 4) = h;
        }
    }
}

// ---------------------------------------------------------------------------
// Split-K-in-block MFMA GEMM body on swizzled fp16 weights (unchanged).
// ---------------------------------------------------------------------------
template<int CTN, int NSUM, bool A2SW, bool LNA>
__device__ __forceinline__ void gemm_body(int bx, int by, int tid,
    float* redu, float* sst, float* sst2,
    const h16* __restrict__ A16, int lda, int sumStride,
    const float* __restrict__ A32,
    const float* __restrict__ lng, const float* __restrict__ lnb,
    float* __restrict__ lnout,
    const h16* __restrict__ A2_16, int a2Start,
    const h16* __restrict__ Wswz,
    const float* __restrict__ B0, const float* __restrict__ B1, const float* __restrict__ B2s,
    const float* __restrict__ R, int ldr,
    float* __restrict__ C32, h16* __restrict__ C16, int ldc,
    int K, int act)
{
    int w = tid >> 6, l = tid & 63;
    int lr = l & 15, q4 = l >> 4;
    int m0 = by * 16;
    int n0 = bx * 16 * CTN;
    int row = m0 + lr;
    int K32 = K >> 5;
    int KQ = K32 >> 2;
    int ks0 = w * KQ;

    bool useA2 = A2SW && (bx >= a2Start);

    const float* arow32 = nullptr;
    float mean = 0.f, rstd = 1.f;
    if (LNA && !useA2) {
        arow32 = A32 + (size_t)row * K + q4 * 8;
        float s = 0.f, s2 = 0.f;
        for (int ks = ks0; ks < ks0 + KQ; ks++) {
            float4 u = *(const float4*)(arow32 + ks * 32);
            float4 v = *(const float4*)(arow32 + ks * 32 + 4);
            s  += u.x + u.y + u.z + u.w + v.x + v.y + v.z + v.w;
            s2 += u.x*u.x + u.y*u.y + u.z*u.z + u.w*u.w
                + v.x*v.x + v.y*v.y + v.z*v.z + v.w*v.w;
        }
        s  += __shfl_xor(s, 16);  s  += __shfl_xor(s, 32);
        s2 += __shfl_xor(s2, 16); s2 += __shfl_xor(s2, 32);
        if (q4 == 0) { sst[w * 16 + lr] = s; sst2[w * 16 + lr] = s2; }
        __syncthreads();
        float st = sst[lr] + sst[16 + lr] + sst[32 + lr] + sst[48 + lr];
        float st2 = sst2[lr] + sst2[16 + lr] + sst2[32 + lr] + sst2[48 + lr];
        mean = st * (1.0f / (float)K);
        float var = st2 * (1.0f / (float)K) - mean * mean;
        rstd = rsqrtf(var + 1e-5f);
    }

    const h16* arow16 = nullptr;
    if (useA2)       arow16 = A2_16 + (size_t)row * 512 + q4 * 8;
    else if (!LNA)   arow16 = A16 + (size_t)row * lda + q4 * 8;

    const h16* wbase[CTN];
#pragma unroll
    for (int ct = 0; ct < CTN; ct++) {
        int tct = (n0 >> 4) + ct;
        wbase[ct] = Wswz + (((size_t)(tct >> 2) * K32 * 4 + (tct & 3)) * 64 + l) * 8;
    }

    f32x4 acc[CTN];
#pragma unroll
    for (int ct = 0; ct < CTN; ct++) acc[ct] = (f32x4){0.f, 0.f, 0.f, 0.f};

    bool wrln = LNA && !useA2 && (bx == 0) && lnout;

#pragma unroll 4
    for (int ks = ks0; ks < ks0 + KQ; ks++) {
        half8 a;
        if (LNA && !useA2) {
            float4 u = *(const float4*)(arow32 + ks * 32);
            float4 v = *(const float4*)(arow32 + ks * 32 + 4);
            float4 g0 = *(const float4*)(lng + ks * 32 + q4 * 8);
            float4 g1 = *(const float4*)(lng + ks * 32 + q4 * 8 + 4);
            float4 b0 = *(const float4*)(lnb + ks * 32 + q4 * 8);
            float4 b1 = *(const float4*)(lnb + ks * 32 + q4 * 8 + 4);
            float4 o0, o1;
            o0.x = (u.x - mean) * rstd * g0.x + b0.x;
            o0.y = (u.y - mean) * rstd * g0.y + b0.y;
            o0.z = (u.z - mean) * rstd * g0.z + b0.z;
            o0.w = (u.w - mean) * rstd * g0.w + b0.w;
            o1.x = (v.x - mean) * rstd * g1.x + b1.x;
            o1.y = (v.y - mean) * rstd * g1.y + b1.y;
            o1.z = (v.z - mean) * rstd * g1.z + b1.z;
            o1.w = (v.w - mean) * rstd * g1.w + b1.w;
            if (wrln) {
                *(float4*)(lnout + (size_t)row * K + ks * 32 + q4 * 8)     = o0;
                *(float4*)(lnout + (size_t)row * K + ks * 32 + q4 * 8 + 4) = o1;
            }
            a = pack8(o0, o1);
        } else if (NSUM == 1) {
            a = *(const half8*)(arow16 + (size_t)ks * 32);
        } else {
            float s[8] = {0.f, 0.f, 0.f, 0.f, 0.f, 0.f, 0.f, 0.f};
#pragma unroll
            for (int j = 0; j < NSUM; j++) {
                half8 tt = *(const half8*)(arow16 + (size_t)j * sumStride + ks * 32);
#pragma unroll
                for (int e = 0; e < 8; e++) s[e] += (float)tt[e];
            }
#pragma unroll
            for (int e = 0; e < 8; e++) a[e] = (h16)s[e];
        }
#pragma unroll
        for (int ct = 0; ct < CTN; ct++) {
            half8 bfr = *(const half8*)(wbase[ct] + (size_t)ks * 2048);
            acc[ct] = __builtin_amdgcn_mfma_f32_16x16x32_f16(a, bfr, acc[ct], 0, 0, 0);
        }
    }

#pragma unroll
    for (int ct = 0; ct < CTN; ct++)
        *(f32x4*)&redu[(size_t)(w * CTN + ct) * 256 + l * 4] = acc[ct];
    __syncthreads();

    if (w < CTN) {
        int ct = w;
        f32x4 sum = *(const f32x4*)&redu[(size_t)ct * 256 + l * 4];
#pragma unroll
        for (int w2 = 1; w2 < 4; w2++) {
            f32x4 tt = *(const f32x4*)&redu[(size_t)(w2 * CTN + ct) * 256 + l * 4];
            sum[0] += tt[0]; sum[1] += tt[1]; sum[2] += tt[2]; sum[3] += tt[3];
        }
        int n = n0 + ct * 16 + lr;
        float bv;
        if (B1) { int sec = n >> 9, ni = n & 511;
                  bv = (sec == 0) ? B0[ni] : (sec == 1 ? B1[ni] : B2s[ni]); }
        else bv = B0[n];
#pragma unroll
        for (int r = 0; r < 4; r++) {
            int m = m0 + q4 * 4 + r;
            float v = sum[r] + bv;
            if (act) v = fmaxf(v, 0.f);
            if (R) v += R[(size_t)m * ldr + n];
            if (C32) C32[(size_t)m * ldc + n] = v;
            if (C16) C16[(size_t)m * ldc + n] = (h16)v;
        }
    }
}

// ---- head output body: one wave per (q, n) ----
__device__ __forceinline__ void heads2_body(int q, int n, int lane,
    const h16* __restrict__ hid16,
    const float* __restrict__ w2m, const float* __restrict__ b2m,
    const float* __restrict__ w2t, const float* __restrict__ b2t,
    const float* __restrict__ w2a, const float* __restrict__ b2a,
    const float* __restrict__ pmin, const float* __restrict__ pmax,
    float* __restrict__ out)
{
    const float* wr; float bv; int mode, sect;
    if (n < 11)      { sect = 0; wr = w2m + n * 512;        bv = b2m[n];      mode = 0; }
    else if (n < 21) { sect = 1; wr = w2t + (n - 11) * 512; bv = b2t[n - 11]; mode = 1; }
    else             { sect = 2; wr = w2a + (n - 21) * 512; bv = b2a[n - 21]; mode = 2; }
    half8 hv = *(const half8*)(hid16 + q * 1536 + sect * 512 + lane * 8);
    const float4* w4 = (const float4*)(wr + lane * 8);
    float4 c0 = w4[0], c1 = w4[1];
    float acc = (float)hv[0] * c0.x + (float)hv[1] * c0.y
              + (float)hv[2] * c0.z + (float)hv[3] * c0.w
              + (float)hv[4] * c1.x + (float)hv[5] * c1.y
              + (float)hv[6] * c1.z + (float)hv[7] * c1.w;
    for (int off = 32; off; off >>= 1) acc += __shfl_xor(acc, off);
    if (lane == 0) {
        float v = acc + bv;
        if (mode == 0)      v = (1.0f / (1.0f + __expf(-v))) * (pmax[n] - pmin[n]) + pmin[n];
        else if (mode == 2) v = 1.0f / (1.0f + __expf(-v));
        out[q * 24 + n] = v;
    }
}

// ---- MHA core body on packed qkv (128 x 1536 = [Q|K|V] fp32) ----
__device__ __forceinline__ void attn_body(int bid, int tid,
                                          float* KVl, float* Ql, float* Pl,
                                          const float* __restrict__ qkv,
                                          h16* __restrict__ out16)
{
    int h = bid >> 2, chunk = bid & 3;

    for (int l = tid; l < 2048; l += 256) {
        int row = l >> 4, c4 = (l & 15) * 4;
        float4 v = *(const float4*)&qkv[row * 1536 + 512 + h * 64 + c4];
        *(float4*)&KVl[row * 68 + c4] = v;
    }
    for (int l = tid; l < 512; l += 256) {
        int row = l >> 4, c4 = (l & 15) * 4;
        float4 v = *(const float4*)&qkv[(chunk * 32 + row) * 1536 + h * 64 + c4];
        *(float4*)&Ql[row * 68 + c4] = v;
    }
    __syncthreads();

    int w = tid >> 6, j = tid & 63;
    for (int r8 = 0; r8 < 8; r8++) {
        int lr = w * 8 + r8;
        float s0 = 0.f, s1 = 0.f;
#pragma unroll
        for (int k4 = 0; k4 < 64; k4 += 4) {
            float4 qv  = *(const float4*)&Ql[lr * 68 + k4];
            float4 k0v = *(const float4*)&KVl[j * 68 + k4];
            float4 k1v = *(const float4*)&KVl[(j + 64) * 68 + k4];
            s0 += qv.x * k0v.x + qv.y * k0v.y + qv.z * k0v.z + qv.w * k0v.w;
            s1 += qv.x * k1v.x + qv.y * k1v.y + qv.z * k1v.z + qv.w * k1v.w;
        }
        s0 *= 0.125f; s1 *= 0.125f;
        float m = fmaxf(s0, s1);
        for (int off = 32; off; off >>= 1) m = fmaxf(m, __shfl_xor(m, off));
        float e0 = __expf(s0 - m), e1 = __expf(s1 - m);
        float sm = e0 + e1;
        for (int off = 32; off; off >>= 1) sm += __shfl_xor(sm, off);
        float inv = 1.0f / sm;
        Pl[lr * 128 + j]      = e0 * inv;
        Pl[lr * 128 + j + 64] = e1 * inv;
    }
    __syncthreads();

    for (int l = tid; l < 2048; l += 256) {
        int row = l >> 4, c4 = (l & 15) * 4;
        float4 v = *(const float4*)&qkv[row * 1536 + 1024 + h * 64 + c4];
        KVl[(c4 + 0) * 132 + row] = v.x;
        KVl[(c4 + 1) * 132 + row] = v.y;
        KVl[(c4 + 2) * 132 + row] = v.z;
        KVl[(c4 + 3) * 132 + row] = v.w;
    }
    __syncthreads();

    int d = tid & 63, w2 = tid >> 6;
    for (int r8 = 0; r8 < 8; r8++) {
        int lr = w2 * 8 + r8;
        float o = 0.f;
#pragma unroll
        for (int j4 = 0; j4 < 128; j4 += 4) {
            float4 pv = *(const float4*)&Pl[lr * 128 + j4];
            float4 vv = *(const float4*)&KVl[d * 132 + j4];
            o += pv.x * vv.x + pv.y * vv.y + pv.z * vv.z + pv.w * vv.w;
        }
        out16[(chunk * 32 + lr) * 512 + h * 64 + d] = (h16)o;
    }
}

// ---- gather body (no early return; mega-safe) ----
__device__ __forceinline__ float bflo(unsigned u) {
    union { unsigned i; float f; } c; c.i = u << 16; return c.f;
}
__device__ __forceinline__ float bfhi(unsigned u) {
    union { unsigned i; float f; } c; c.i = u & 0xffff0000u; return c.f;
}

__device__ __forceinline__ void gather_body(int n, int cam, int tid, float* smem,
                                            const bf16* __restrict__ ft,
                                            const float* __restrict__ proj,
                                            const float* __restrict__ preds,
                                            h16* __restrict__ agg16)
{
    float* part = smem;                    // 2048 floats
    float* mo   = smem + 2048;             // 11
    float* gw   = smem + 2064;             // 384
    int*   goff = (int*)(smem + 2448);     // 384
    int*   cnt  = (int*)(smem + 2832);

    if (tid == 0) *cnt = 0;
    if (tid < 11) mo[tid] = preds[n * 24 + tid];
    __syncthreads();

    if (tid < 96) {
        int p = tid;
        float dd0 = mo[8], dd1 = mo[9], dd2 = mo[10];
        float c0 = mo[0], c1 = mo[1], c2 = mo[2];
        float sy, cy;
        sincosf(mo[7], &sy, &cy);
        int face = p >> 4, axis = face >> 1;
        float sgn = (face & 1) ? 0.5f : -0.5f;
        float offi = -0.4f + (float)((p >> 2) & 3) * (0.8f / 3.0f);
        float offj = -0.4f + (float)(p & 3) * (0.8f / 3.0f);
        float t0, t1, t2;
        if (axis == 0)      { t0 = sgn;  t1 = offi; t2 = offj; }
        else if (axis == 1) { t0 = offi; t1 = sgn;  t2 = offj; }
        else                { t0 = offi; t1 = offj; t2 = sgn;  }
        float px = t0 * dd0, py = t1 * dd1, pz = t2 * dd2;
        float X = px * cy - py * sy + c0;
        float Y = px * sy + py * cy + c1;
        float Z = pz + c2;
        const float* P = proj + cam * 12;
        float cu = P[0] * X + P[1] * Y + P[2] * Z + P[3];
        float cv = P[4] * X + P[5] * Y + P[6] * Z + P[7];
        float cz = P[8] * X + P[9] * Y + P[10] * Z + P[11];
        float zs = (fabsf(cz) > 1e-6f) ? cz : 1e-6f;
        float u = cu / zs, v = cv / zs;
        bool front = cz > 0.0f;
        float u0 = floorf(u), v0 = floorf(v);
        float du = u - u0, dv = v - v0;
        float us[4] = {u0, u0 + 1.0f, u0, u0 + 1.0f};
        float vs[4] = {v0, v0, v0 + 1.0f, v0 + 1.0f};
        float wt[4] = {(1.0f - du) * (1.0f - dv), du * (1.0f - dv),
                       (1.0f - du) * dv, du * dv};
        int   myoff[4]; float myw[4]; int k = 0;
#pragma unroll
        for (int t = 0; t < 4; t++) {
            bool ok = front && (us[t] >= 0.0f) && (us[t] <= 119.0f)
                            && (vs[t] >= 0.0f) && (vs[t] <= 47.0f)
                            && (wt[t] > 0.0f);
            if (ok) {
                myoff[k] = ((int)vs[t] * IMW + (int)us[t]) * FD;
                myw[k]   = wt[t];
                k++;
            }
        }
        if (k) {
            int base = atomicAdd(cnt, k);
            for (int s = 0; s < k; s++) { goff[base + s] = myoff[s]; gw[base + s] = myw[s]; }
        }
    }
    __syncthreads();
    int C = *cnt;
    h16* slab = agg16 + (size_t)cam * 32768 + n * 256;
    if (C == 0) {
        slab[tid] = (h16)0.f;
    } else {
        int g8  = (tid & 31) * 8;
        int row = tid >> 5;
        const bf16* fb = ft + (size_t)cam * HW * FD + g8;
        float acc[8] = {0.f, 0.f, 0.f, 0.f, 0.f, 0.f, 0.f, 0.f};
        for (int e = row; e < C; e += 8) {
            float w = gw[e];
            uint4 rv = *(const uint4*)(fb + goff[e]);
            acc[0] += w * bflo(rv.x); acc[1] += w * bfhi(rv.x);
            acc[2] += w * bflo(rv.y); acc[3] += w * bfhi(rv.y);
            acc[4] += w * bflo(rv.z); acc[5] += w * bfhi(rv.z);
            acc[6] += w * bflo(rv.w); acc[7] += w * bfhi(rv.w);
        }
#pragma unroll
        for (int j = 0; j < 8; j++) part[row * 256 + g8 + j] = acc[j];
        __syncthreads();
        float s = 0.f;
#pragma unroll
        for (int r = 0; r < 8; r++) s += part[r * 256 + tid];
        slab[tid] = (h16)(s * (1.0f / 576.0f));
    }
}

// ---------------------------------------------------------------------------
// Mega kernel: entire 6-layer decoder loop, persistent, manual grid barrier.
// ---------------------------------------------------------------------------
struct MegaP {
    const h16* swz;
    const float* queries0;
    const h16* q016;
    const bf16* feat_t;
    const float* proj;
    const float *motion_b1, *type_b1, *attr_b1;
    const float *motion_w2, *motion_b2, *type_w2, *type_b2, *attr_w2, *attr_b2;
    const float *pmin, *pmax;
    const float *fmlp_b1, *fmlp_b2;
    const float *sa_in_b, *sa_out_b, *fa_in_b, *fa_out_b, *ffn_b1, *ffn_b2;
    const float *ln1_g, *ln1_b, *ln2_g, *ln2_b, *ln3_g, *ln3_b;
    h16 *hid16, *agg16, *fmlph16, *feath16, *attnb16, *ffnh16, *qn16;
    float *qkv, *lnx, *x1, *x2, *qn32;
    float* out;
    unsigned* bar;
};

__global__ __launch_bounds__(256, 2) void mega_k(MegaP P)
{
    __shared__ float smem[14976];   // 59904B: attn KVl 8704 | Ql 2176 | Pl 4096
    int bid = blockIdx.x, tid = threadIdx.x;
    int GS = gridDim.x;
    unsigned tgt = 0;

    const h16* sw_heads = P.swz;
    const h16* sw_fmlp1 = P.swz + 786432;
    const h16* sw_fmlp2 = P.swz + 917504;
    const h16* sw_sain  = P.swz + 1179648;
    const h16* sw_saout = P.swz + 5898240;
    const h16* sw_fain  = P.swz + 7471104;
    const h16* sw_faout = P.swz + 12189696;
    const h16* sw_ffn1  = P.swz + 13762560;
    const h16* sw_ffn2  = P.swz + 20054016;

    const h16*   q16 = P.q016;
    const float* q32 = P.queries0;

    for (int i = 0; i < 6; i++) {
        // P1: heads hidden GEMM (384 units)
        for (int u = bid; u < 384; u += GS) {
            __syncthreads();
            gemm_body<2, 1, false, false>(u % 48, u / 48, tid,
                smem, smem + 2048, smem + 2112,
                q16, 512, 0, nullptr, nullptr, nullptr, nullptr, nullptr, 0,
                sw_heads, P.motion_b1, P.type_b1, P.attr_b1, nullptr, 0,
                nullptr, P.hid16, 1536, 512, 1);
        }
        gbar(P.bar, GS, &tgt);

        if (i == 5) {
            // final heads2 only (768 units x 4 waves)
            for (int u = bid; u < 768; u += GS) {
                int p = (u << 2) + (tid >> 6);
                heads2_body(p / 24, p % 24, tid & 63, P.hid16,
                            P.motion_w2, P.motion_b2, P.type_w2, P.type_b2,
                            P.attr_w2, P.attr_b2, P.pmin, P.pmax, P.out + i * 3072);
            }
            break;
        }

        // P2: sa_in GEMM (384) + heads2 (768)
        for (int u = bid; u < 1152; u += GS) {
            __syncthreads();
            if (u < 384) {
                gemm_body<2, 1, false, true>(u % 48, u / 48, tid,
                    smem, smem + 2048, smem + 2112,
                    nullptr, 0, 0, q32, P.ln1_g + i * 512, P.ln1_b + i * 512, P.lnx,
                    nullptr, 0,
                    sw_sain + (size_t)i * 786432, P.sa_in_b + i * 1536, nullptr, nullptr,
                    nullptr, 0, P.qkv, nullptr, 1536, 512, 0);
            } else {
                int p = ((u - 384) << 2) + (tid >> 6);
                heads2_body(p / 24, p % 24, tid & 63, P.hid16,
                            P.motion_w2, P.motion_b2, P.type_w2, P.type_b2,
                            P.attr_w2, P.attr_b2, P.pmin, P.pmax, P.out + i * 3072);
            }
        }
        gbar(P.bar, GS, &tgt);

        // P3: attn-self (32) + gather (768)
        for (int u = bid; u < 800; u += GS) {
            __syncthreads();
            if (u < 32) {
                attn_body(u, tid, smem, smem + 8704, smem + 10880, P.qkv, P.attnb16);
            } else {
                int v = u - 32;
                gather_body(v % 128, v / 128, tid, smem, P.feat_t, P.proj,
                            P.out + i * 3072, P.agg16);
            }
        }
        gbar(P.bar, GS, &tgt);

        // P4: fmlp1 (256) + sa_out (256)
        for (int u = bid; u < 512; u += GS) {
            __syncthreads();
            if (u < 256) {
                gemm_body<1, 6, false, false>(u % 32, u / 32, tid,
                    smem, smem + 1024, smem + 1088,
                    P.agg16, 256, 32768, nullptr, nullptr, nullptr, nullptr, nullptr, 0,
                    sw_fmlp1, P.fmlp_b1, nullptr, nullptr, nullptr, 0,
                    nullptr, P.fmlph16, 512, 256, 1);
            } else {
                int v = u - 256;
                gemm_body<1, 1, false, false>(v % 32, v / 32, tid,
                    smem, smem + 1024, smem + 1088,
                    P.attnb16, 512, 0, nullptr, nullptr, nullptr, nullptr, nullptr, 0,
                    sw_saout + (size_t)i * 262144, P.sa_out_b + i * 512, nullptr, nullptr,
                    P.lnx, 512, P.x1, nullptr, 512, 512, 0);
            }
        }
        gbar(P.bar, GS, &tgt);

        // P5: fmlp2 (256)
        for (int u = bid; u < 256; u += GS) {
            __syncthreads();
            gemm_body<1, 1, false, false>(u % 32, u / 32, tid,
                smem, smem + 1024, smem + 1088,
                P.fmlph16, 512, 0, nullptr, nullptr, nullptr, nullptr, nullptr, 0,
                sw_fmlp2, P.fmlp_b2, nullptr, nullptr, nullptr, 0,
                nullptr, P.feath16, 512, 512, 0);
        }
        gbar(P.bar, GS, &tgt);

        // P6: fa_in (384; kv side reads feath16 for bx>=16)
        for (int u = bid; u < 384; u += GS) {
            __syncthreads();
            gemm_body<2, 1, true, true>(u % 48, u / 48, tid,
                smem, smem + 2048, smem + 2112,
                nullptr, 0, 0, P.x1, P.ln2_g + i * 512, P.ln2_b + i * 512, P.lnx,
                P.feath16, 16,
                sw_fain + (size_t)i * 786432, P.fa_in_b + i * 1536, nullptr, nullptr,
                nullptr, 0, P.qkv, nullptr, 1536, 512, 0);
        }
        gbar(P.bar, GS, &tgt);

        // P7: attn-cross (32)
        for (int u = bid; u < 32; u += GS) {
            __syncthreads();
            attn_body(u, tid, smem, smem + 8704, smem + 10880, P.qkv, P.attnb16);
        }
        gbar(P.bar, GS, &tgt);

        // P8: fa_out (256)
        for (int u = bid; u < 256; u += GS) {
            __syncthreads();
            gemm_body<1, 1, false, false>(u % 32, u / 32, tid,
                smem, smem + 1024, smem + 1088,
                P.attnb16, 512, 0, nullptr, nullptr, nullptr, nullptr, nullptr, 0,
                sw_faout + (size_t)i * 262144, P.fa_out_b + i * 512, nullptr, nullptr,
                P.lnx, 512, P.x2, nullptr, 512, 512, 0);
        }
        gbar(P.bar, GS, &tgt);

        // P9: ffn1 (512)
        for (int u = bid; u < 512; u += GS) {
            __syncthreads();
            gemm_body<2, 1, false, true>(u % 64, u / 64, tid,
                smem, smem + 2048, smem + 2112,
                nullptr, 0, 0, P.x2, P.ln3_g + i * 512, P.ln3_b + i * 512, P.lnx,
                nullptr, 0,
                sw_ffn1 + (size_t)i * 1048576, P.ffn_b1 + i * 2048, nullptr, nullptr,
                nullptr, 0, nullptr, P.ffnh16, 2048, 512, 1);
        }
        gbar(P.bar, GS, &tgt);

        // P10: ffn2 (256)
        for (int u = bid; u < 256; u += GS) {
            __syncthreads();
            gemm_body<1, 1, false, false>(u % 32, u / 32, tid,
                smem, smem + 1024, smem + 1088,
                P.ffnh16, 2048, 0, nullptr, nullptr, nullptr, nullptr, nullptr, 0,
                sw_ffn2 + (size_t)i * 1048576, P.ffn_b2 + i * 512, nullptr, nullptr,
                P.lnx, 512, P.qn32, P.qn16, 512, 2048, 0);
        }
        gbar(P.bar, GS, &tgt);

        q16 = P.qn16;
        q32 = P.qn32;
    }
}

// ---------------------------------------------------------------------------
extern "C" void kernel_launch(void* const* d_in, const int* in_sizes, int n_in,
                              void* d_out, int out_size, void* d_ws, size_t ws_size,
                              hipStream_t stream)
{
    const float* features  = (const float*)d_in[0];
    const float* proj      = (const float*)d_in[1];
    const float* queries0  = (const float*)d_in[3];
    const float* pmin      = (const float*)d_in[4];
    const float* pmax      = (const float*)d_in[5];
    const float* motion_w1 = (const float*)d_in[6];
    const float* motion_b1 = (const float*)d_in[7];
    const float* motion_w2 = (const float*)d_in[8];
    const float* motion_b2 = (const float*)d_in[9];
    const float* type_w1   = (const float*)d_in[10];
    const float* type_b1   = (const float*)d_in[11];
    const float* type_w2   = (const float*)d_in[12];
    const float* type_b2   = (const float*)d_in[13];
    const float* attr_w1   = (const float*)d_in[14];
    const float* attr_b1   = (const float*)d_in[15];
    const float* attr_w2   = (const float*)d_in[16];
    const float* attr_b2   = (const float*)d_in[17];
    const float* fmlp_w1   = (const float*)d_in[18];
    const float* fmlp_b1   = (const float*)d_in[19];
    const float* fmlp_w2   = (const float*)d_in[20];
    const float* fmlp_b2   = (const float*)d_in[21];
    const float* sa_in_w   = (const float*)d_in[22];
    const float* sa_in_b   = (const float*)d_in[23];
    const float* sa_out_w  = (const float*)d_in[24];
    const float* sa_out_b  = (const float*)d_in[25];
    const float* fa_in_w   = (const float*)d_in[26];
    const float* fa_in_b   = (const float*)d_in[27];
    const float* fa_out_w  = (const float*)d_in[28];
    const float* fa_out_b  = (const float*)d_in[29];
    const float* ffn_w1    = (const float*)d_in[30];
    const float* ffn_b1    = (const float*)d_in[31];
    const float* ffn_w2    = (const float*)d_in[32];
    const float* ffn_b2    = (const float*)d_in[33];
    const float* ln1_g     = (const float*)d_in[34];
    const float* ln1_b     = (const float*)d_in[35];
    const float* ln2_g     = (const float*)d_in[36];
    const float* ln2_b     = (const float*)d_in[37];
    const float* ln3_g     = (const float*)d_in[38];
    const float* ln3_b     = (const float*)d_in[39];
    float* out = (float*)d_out;

    // ---- workspace ----
    char* p = (char*)d_ws;
    bf16* feat_t = (bf16*)p;   p += (size_t)NC * HW * FD * 2;        // 17.7 MB
    h16* swz     = (h16*)p;    p += (size_t)51456 * 512 * 2;         // 52.7 MB
    h16* q016    = (h16*)p;    p += 65536 * 2;
    h16* hid16   = (h16*)p;    p += 196608 * 2;
    h16* agg16   = (h16*)p;    p += 196608 * 2;
    h16* fmlph16 = (h16*)p;    p += 65536 * 2;
    h16* feath16 = (h16*)p;    p += 65536 * 2;
    h16* attnb16 = (h16*)p;    p += 65536 * 2;
    h16* ffnh16  = (h16*)p;    p += 262144 * 2;
    h16* qn16    = (h16*)p;    p += 65536 * 2;
    float* qkv   = (float*)p;  p += 196608 * 4;
    float* lnx   = (float*)p;  p += 65536 * 4;
    float* x1    = (float*)p;  p += 65536 * 4;
    float* x2    = (float*)p;  p += 65536 * 4;
    float* qn32  = (float*)p;  p += 65536 * 4;
    unsigned* bar = (unsigned*)p; p += 256;

    // ---- one-time prep (direct swizzle + transpose + cvt + bar zero) ----
    SwzDesc sd;
    const float* srcs[11] = {motion_w1, type_w1, attr_w1, fmlp_w1, fmlp_w2,
                             sa_in_w, sa_out_w, fa_in_w, fa_out_w, ffn_w1, ffn_w2};
    int Ks[11]    = {512, 512, 512, 256, 512, 512, 512, 512, 512, 512, 2048};
    int tiles[11] = {512, 512, 512, 256, 512, 9216, 3072, 9216, 3072, 12288, 12288};
    unsigned int cumT = 0;
    for (int i = 0; i < 11; i++) {
        sd.src[i] = srcs[i]; sd.K[i] = Ks[i];
        sd.tileStart[i] = cumT;
        cumT += tiles[i];
    }
    sd.tileStart[11] = cumT;   // 51456

    prep2_k<<<2160, 256, 0, stream>>>(sd, swz, features, feat_t, queries0, q016, bar);

    // ---- mega kernel (persistent, manual barrier) ----
    MegaP mp;
    mp.swz = swz; mp.queries0 = queries0; mp.q016 = q016;
    mp.feat_t = feat_t; mp.proj = proj;
    mp.motion_b1 = motion_b1; mp.type_b1 = type_b1; mp.attr_b1 = attr_b1;
    mp.motion_w2 = motion_w2; mp.motion_b2 = motion_b2;
    mp.type_w2 = type_w2; mp.type_b2 = type_b2;
    mp.attr_w2 = attr_w2; mp.attr_b2 = attr_b2;
    mp.pmin = pmin; mp.pmax = pmax;
    mp.fmlp_b1 = fmlp_b1; mp.fmlp_b2 = fmlp_b2;
    mp.sa_in_b = sa_in_b; mp.sa_out_b = sa_out_b;
    mp.fa_in_b = fa_in_b; mp.fa_out_b = fa_out_b;
    mp.ffn_b1 = ffn_b1; mp.ffn_b2 = ffn_b2;
    mp.ln1_g = ln1_g; mp.ln1_b = ln1_b; mp.ln2_g = ln2_g; mp.ln2_b = ln2_b;
    mp.ln3_g = ln3_g; mp.ln3_b = ln3_b;
    mp.hid16 = hid16; mp.agg16 = agg16; mp.fmlph16 = fmlph16;
    mp.feath16 = feath16; mp.attnb16 = attnb16; mp.ffnh16 = ffnh16;
    mp.qn16 = qn16;
    mp.qkv = qkv; mp.lnx = lnx; mp.x1 = x1; mp.x2 = x2; mp.qn32 = qn32;
    mp.out = out;
    mp.bar = bar;

    mega_k<<<MEGA_GRID, 256, 0, stream>>>(mp);
}